// Round 3
// baseline (219.736 us; speedup 1.0000x reference)
//
#include <hip/hip_runtime.h>
#include <hip/hip_bf16.h>

typedef short s16x8 __attribute__((ext_vector_type(8)));
typedef float f32x4 __attribute__((ext_vector_type(4)));
typedef float f32x16 __attribute__((ext_vector_type(16)));

__device__ __forceinline__ float b2f(unsigned short u) {
    union { unsigned int i; float f; } v;
    v.i = ((unsigned int)u) << 16;
    return v.f;
}
// packed fp32x2 -> bf16x2 (v_cvt_pk_bf16_f32 on gfx950); lo = a, hi = b
__device__ __forceinline__ unsigned int pkbf16(float a, float b) {
    union { __hip_bfloat162 h; unsigned int u; } v;
    v.h = __float22bfloat162_rn(make_float2(a, b));
    return v.u;
}
// raw v_exp_f32 — libm exp2f adds clamp/scale VALU (measured regression r5)
__device__ __forceinline__ float fast_exp2(float x) {
#if __has_builtin(__builtin_amdgcn_exp2f)
    return __builtin_amdgcn_exp2f(x);
#else
    return exp2f(x);
#endif
}

// async global->LDS, 16B/lane; LDS dest = wave-uniform base + lane*16
__device__ __forceinline__ void gl_lds16(const unsigned short* g, unsigned short* l) {
    __builtin_amdgcn_global_load_lds(
        (const __attribute__((address_space(1))) void*)g,
        (__attribute__((address_space(3))) void*)l, 16, 0, 0);
}

// v_permlane32_swap_b32: new_a = [a_lo | b_lo], new_b = [a_hi | b_hi]
__device__ __forceinline__ void perm32swap(unsigned int &a, unsigned int &b) {
    asm("v_permlane32_swap_b32 %0, %1" : "+v"(a), "+v"(b));
}

// assemble s16x8 fragment from 4 packed bf16x2 words
__device__ __forceinline__ s16x8 mk8(unsigned int a, unsigned int b,
                                     unsigned int c, unsigned int d) {
    union { uint4 u; s16x8 h; } v;
    v.u = make_uint4(a, b, c, d);
    return v.h;
}

// ---------------------------------------------------------------------------
// Merged fp32->bf16 converts + bias pack, one launch.
// ---------------------------------------------------------------------------
__device__ __forceinline__ void cvt8(const float* __restrict__ s,
                                     unsigned short* __restrict__ d, int i) {
    const float* p = s + (size_t)i * 8;
    float4 a = *(const float4*)p;
    float4 b = *(const float4*)(p + 4);
    unsigned int u0 = pkbf16(a.x, a.y), u1 = pkbf16(a.z, a.w);
    unsigned int u2 = pkbf16(b.x, b.y), u3 = pkbf16(b.z, b.w);
    uint4 o = {u0, u1, u2, u3};
    *(uint4*)&d[(size_t)i * 8] = o;
}

__global__ __launch_bounds__(256) void cvt_main(
    const float* __restrict__ x,  const float* __restrict__ Wq,
    const float* __restrict__ Wk, const float* __restrict__ Wv,
    const float* __restrict__ Wr, const float* __restrict__ Ws,
    const float* __restrict__ bq, const float* __restrict__ bk,
    const float* __restrict__ bv,
    unsigned short* __restrict__ xb, unsigned short* __restrict__ wqkv,
    unsigned short* __restrict__ wg, float* __restrict__ bqkv)
{
    int blk = blockIdx.x, t = threadIdx.x;
    if (blk < 2048)      cvt8(x,  xb,             blk * 256 + t);
    else if (blk < 2560) cvt8(Wq, wqkv,           (blk - 2048) * 256 + t);
    else if (blk < 3072) cvt8(Wk, wqkv + 1048576, (blk - 2560) * 256 + t);
    else if (blk < 3584) cvt8(Wv, wqkv + 2097152, (blk - 3072) * 256 + t);
    else if (blk < 3592) { int i = (blk - 3584) * 256 + t; if (i < 1920) cvt8(Wr, wg, i); }
    else if (blk < 3593) { int i = t; cvt8(Ws, wg + 15360, i); }
    else {
        int i = (blk - 3593) * 256 + t;  // 0..3071
        bqkv[i] = (i < 1024) ? bq[i] : (i < 2048) ? bk[i - 1024] : bv[i - 2048];
    }
}

// ---------------------------------------------------------------------------
// QKV GEMM: C = xb[4096][1024] * Wqkv[3072][1024]^T + bias.
// 128x128 tile, BK=64, swizzled LDS + global_load_lds.
// n0<1024 -> Q; <2048 -> K; else V written transposed to Vt[b,h,d,tok].
// ---------------------------------------------------------------------------
__global__ __launch_bounds__(256) void qkv_gemm(
    const unsigned short* __restrict__ A,
    const unsigned short* __restrict__ Bw,
    const float* __restrict__ bias,
    unsigned short* __restrict__ Q, unsigned short* __restrict__ K,
    unsigned short* __restrict__ Vt)
{
    __shared__ __attribute__((aligned(16))) unsigned short As[128 * 64];
    __shared__ __attribute__((aligned(16))) unsigned short Bs[128 * 64];
    const int t = threadIdx.x;
    const int wave = t >> 6, lane = t & 63;
    const int m0 = blockIdx.x * 128, n0 = blockIdx.y * 128;
    const int wm = (wave >> 1) * 64, wn = (wave & 1) * 64;
    const int lr = lane & 15, lq = lane >> 4;
    const int srow = lane >> 3;
    const int scol = (((lane & 7) ^ srow) << 3);

    f32x4 acc[4][4];
#pragma unroll
    for (int i = 0; i < 4; ++i)
#pragma unroll
        for (int j = 0; j < 4; ++j) acc[i][j] = (f32x4){0.f, 0.f, 0.f, 0.f};

    for (int k0 = 0; k0 < 1024; k0 += 64) {
        __syncthreads();
#pragma unroll
        for (int i = 0; i < 4; ++i) {
            int rb = wave * 32 + i * 8;
            gl_lds16(&A[(size_t)(m0 + rb + srow) * 1024 + k0 + scol], &As[rb * 64]);
            gl_lds16(&Bw[(size_t)(n0 + rb + srow) * 1024 + k0 + scol], &Bs[rb * 64]);
        }
        __syncthreads();
#pragma unroll
        for (int kk = 0; kk < 64; kk += 32) {
            const int po = ((((kk >> 3) + lq) ^ (lr & 7)) << 3);
            s16x8 af[4], bf[4];
#pragma unroll
            for (int i = 0; i < 4; ++i)
                af[i] = *(const s16x8*)&As[(wm + i * 16 + lr) * 64 + po];
#pragma unroll
            for (int j = 0; j < 4; ++j)
                bf[j] = *(const s16x8*)&Bs[(wn + j * 16 + lr) * 64 + po];
#pragma unroll
            for (int i = 0; i < 4; ++i)
#pragma unroll
                for (int j = 0; j < 4; ++j)
                    acc[i][j] = __builtin_amdgcn_mfma_f32_16x16x32_bf16(af[i], bf[j], acc[i][j], 0, 0, 0);
        }
    }
    const int kind = n0 >> 10;        // 0=Q 1=K 2=V
    const int nc = n0 & 1023;
    if (kind < 2) {
        unsigned short* Cm = kind ? K : Q;
#pragma unroll
        for (int j = 0; j < 4; ++j) {
            int cl = wn + j * 16 + lr;
            float bv = bias[n0 + cl];
#pragma unroll
            for (int i = 0; i < 4; ++i) {
                int rowb = m0 + wm + i * 16 + lq * 4;
                unsigned int u0 = pkbf16(acc[i][j][0] + bv, acc[i][j][1] + bv);
                unsigned int u1 = pkbf16(acc[i][j][2] + bv, acc[i][j][3] + bv);
                Cm[(size_t)(rowb + 0) * 1024 + nc + cl] = (unsigned short)u0;
                Cm[(size_t)(rowb + 1) * 1024 + nc + cl] = (unsigned short)(u0 >> 16);
                Cm[(size_t)(rowb + 2) * 1024 + nc + cl] = (unsigned short)u1;
                Cm[(size_t)(rowb + 3) * 1024 + nc + cl] = (unsigned short)(u1 >> 16);
            }
        }
    } else {
        // V -> Vt[b,h,d,tok]: 4 consecutive tokens per lane = 8B contiguous
        const int bb = m0 >> 11;
#pragma unroll
        for (int j = 0; j < 4; ++j) {
            int col = nc + wn + j * 16 + lr;      // channel 0..1023
            int hh = col >> 6, dd = col & 63;
            float bv = bias[n0 + wn + j * 16 + lr];
#pragma unroll
            for (int i = 0; i < 4; ++i) {
                int tokb = m0 + wm + i * 16 + lq * 4;
                int tloc = tokb & 2047;
                uint2 u;
                u.x = pkbf16(acc[i][j][0] + bv, acc[i][j][1] + bv);
                u.y = pkbf16(acc[i][j][2] + bv, acc[i][j][3] + bv);
                *(uint2*)&Vt[((size_t)(bb * 16 + hh) * 64 + dd) * 2048 + tloc] = u;
            }
        }
    }
}

// ---------------------------------------------------------------------------
// Flash attention v4 (r14): r13 + T15 two-half software pipeline.
// r13 post-mortem: 4 waves/SIMD, no pipe >55%, wall ~2x hottest pipe (LDS
// ~54%) -> intra-wave serialization with phase-locked waves. Fix: issue BOTH
// halves' QK chains up front (half-0 softmax runs in half-1's MFMA shadow);
// per half, hoist V ds_reads before the exp2 chain (LDS under TRANS), and
// compute the lsum tree after PV issues (VALU under MFMA shadow).
// Everything else (in-block K-split, swapped 32x32x16 MFMA, in-reg softmax
// via cvt_pk + permlane32_swap, double-buffered 64-key chunks) unchanged.
// ---------------------------------------------------------------------------
__global__ __launch_bounds__(512, 4) void attn_kernel(
    const unsigned short* __restrict__ Q,   // raw q [B*N][C]
    const unsigned short* __restrict__ Kb,  // [B*N][C]
    const unsigned short* __restrict__ Vt,  // [B][H][64][N]
    const float* __restrict__ temp,
    const float* __restrict__ qe,
    unsigned short* __restrict__ Hout)      // [B*N][C]
{
    __shared__ __attribute__((aligned(16))) unsigned short Ks[2][2][64 * 64]; // [stream][buf] 32 KB
    __shared__ __attribute__((aligned(16))) unsigned short Vs[2][2][64 * 64]; // 32 KB
    __shared__ float Lred[8][32];                                             // 1 KB
    const int t = threadIdx.x, wave = t >> 6, lane = t & 63;
    const int ws = wave >> 2, wq = wave & 3;   // key-stream, q-subtile wave
    const int l31 = lane & 31, hi = lane >> 5;
    const int bh = blockIdx.x, b = bh >> 4, h = bh & 15;
    const int q0 = blockIdx.y * 128;
    const int srow = lane >> 3;
    const int scol = (((lane & 7) ^ srow) << 3);
    const int kbase = ws << 10;                // stream key offset (0 / 1024)
    unsigned short* KsF = &Ks[0][0][0];        // flat 16 KB region for Q staging

    auto stageK = [&](int kc, int cb) {
#pragma unroll
        for (int i2 = 0; i2 < 2; ++i2) {
            int rb = wq * 16 + i2 * 8;
            gl_lds16(&Kb[(size_t)(b * 2048 + kbase + kc + rb + srow) * 1024 + h * 64 + scol],
                     &Ks[ws][cb][rb * 64]);
        }
    };
    auto stageV = [&](int kc, int cb) {
#pragma unroll
        for (int i2 = 0; i2 < 2; ++i2) {
            int rb = wq * 16 + i2 * 8;
            gl_lds16(&Vt[((size_t)(b * 16 + h) * 64 + rb + srow) * 2048 + kbase + kc + scol],
                     &Vs[ws][cb][rb * 64]);
        }
    };

    // ---- prologue: stage raw Q (swizzled), 8 waves x 16 rows = 128 rows
    {
        int rb = wave * 16;
        gl_lds16(&Q[(size_t)(b * 2048 + q0 + rb + srow) * 1024 + h * 64 + scol],
                 &KsF[rb * 64]);
        gl_lds16(&Q[(size_t)(b * 2048 + q0 + rb + 8 + srow) * 1024 + h * 64 + scol],
                 &KsF[(rb + 8) * 64]);
    }
    __syncthreads();

    // Q fragments: lane (l31,hi) reads q-row wq*32+l31, d = kd*16+hi*8..+7
    s16x8 qf[4];
#pragma unroll
    for (int kd = 0; kd < 4; ++kd)
        qf[kd] = *(const s16x8*)&KsF[(wq * 32 + l31) * 64 + (((kd * 2 + hi) ^ (l31 & 7)) << 3)];
    __syncthreads();   // all Q reads complete before chunk-0 staging reuses Ks

    // issue chunk-0 stage now; the q' VALU math below overlaps its flight
    stageK(0, 0);
    stageV(0, 0);

    // q' = (q/||q|| + qe[h]) * softplus(temp[h]) / (8 ln2), into B-fragments.
    float tv = temp[h];
    float sp = ((tv > 20.f) ? tv : log1pf(__expf(tv))) * 0.18033688f;
    s16x8 aqB[4];
    {
        float v[4][8];
        float ss = 0.f;
#pragma unroll
        for (int kd = 0; kd < 4; ++kd)
#pragma unroll
            for (int e = 0; e < 8; ++e) {
                v[kd][e] = b2f((unsigned short)qf[kd][e]);
                ss += v[kd][e] * v[kd][e];
            }
        ss += __shfl_xor(ss, 32);   // partner lane holds the other 32 d's
        float rn = rsqrtf(ss);
#pragma unroll
        for (int kd = 0; kd < 4; ++kd) {
            const float* qh = qe + h * 64 + kd * 16 + hi * 8;
            unsigned int w0 = pkbf16((v[kd][0] * rn + qh[0]) * sp, (v[kd][1] * rn + qh[1]) * sp);
            unsigned int w1 = pkbf16((v[kd][2] * rn + qh[2]) * sp, (v[kd][3] * rn + qh[3]) * sp);
            unsigned int w2 = pkbf16((v[kd][4] * rn + qh[4]) * sp, (v[kd][5] * rn + qh[5]) * sp);
            unsigned int w3 = pkbf16((v[kd][6] * rn + qh[6]) * sp, (v[kd][7] * rn + qh[7]) * sp);
            aqB[kd] = mk8(w0, w1, w2, w3);
        }
    }

    f32x16 accO[2];
#pragma unroll
    for (int r = 0; r < 16; ++r) { accO[0][r] = 0.f; accO[1][r] = 0.f; }
    float lsum = 0.f;

    for (int it = 0; it < 16; ++it) {
        const int c = it & 1;
        __syncthreads();   // chunk it staged (vmcnt drained); prev-buf reads done
        if (it < 15) { stageK((it + 1) * 64, c ^ 1); stageV((it + 1) * 64, c ^ 1); }

        const int j0 = wave & 1, j1 = j0 ^ 1;   // wave skew preserved

        // ---- T15 phase 1: both QK^T halves (8 chained MFMAs, one prio span)
        s16x8 kf0[4], kf1[4];
#pragma unroll
        for (int kd = 0; kd < 4; ++kd)
            kf0[kd] = *(const s16x8*)&Ks[ws][c][(j0 * 32 + l31) * 64 + (((kd * 2 + hi) ^ (l31 & 7)) << 3)];
#pragma unroll
        for (int kd = 0; kd < 4; ++kd)
            kf1[kd] = *(const s16x8*)&Ks[ws][c][(j1 * 32 + l31) * 64 + (((kd * 2 + hi) ^ (l31 & 7)) << 3)];
        f32x16 s0, s1;
#pragma unroll
        for (int r = 0; r < 16; ++r) { s0[r] = 0.f; s1[r] = 0.f; }
        __builtin_amdgcn_s_setprio(1);
#pragma unroll
        for (int kd = 0; kd < 4; ++kd)
            s0 = __builtin_amdgcn_mfma_f32_32x32x16_bf16(kf0[kd], aqB[kd], s0, 0, 0, 0);
#pragma unroll
        for (int kd = 0; kd < 4; ++kd)
            s1 = __builtin_amdgcn_mfma_f32_32x32x16_bf16(kf1[kd], aqB[kd], s1, 0, 0, 0);
        __builtin_amdgcn_s_setprio(0);

        // ---- T15 phase 2: softmax+PV per half; half-0's softmax runs in
        // half-1's QK MFMA shadow; V reads hoisted ahead of the exp2 chain.
#pragma unroll
        for (int pp = 0; pp < 2; ++pp) {
            const int j = pp ? j1 : j0;
            const f32x16& s = pp ? s1 : s0;
            const int vb0 = (((j * 4 + 0 + hi) ^ (l31 & 7)) << 3);
            const int vb1 = (((j * 4 + 2 + hi) ^ (l31 & 7)) << 3);
            s16x8 v00 = *(const s16x8*)&Vs[ws][c][l31 * 64 + vb0];
            s16x8 v01 = *(const s16x8*)&Vs[ws][c][(32 + l31) * 64 + vb0];
            s16x8 v10 = *(const s16x8*)&Vs[ws][c][l31 * 64 + vb1];
            s16x8 v11 = *(const s16x8*)&Vs[ws][c][(32 + l31) * 64 + vb1];

            float p[16];
#pragma unroll
            for (int r = 0; r < 16; ++r) p[r] = fast_exp2(s[r]);
            unsigned int u[8];
#pragma unroll
            for (int g = 0; g < 8; ++g) u[g] = pkbf16(p[2 * g], p[2 * g + 1]);
            unsigned int a0 = u[0], b0 = u[2], a1 = u[1], b1 = u[3];
            perm32swap(a0, b0); perm32swap(a1, b1);
            s16x8 pf0 = mk8(a0, a1, b0, b1);
            unsigned int a2 = u[4], b2 = u[6], a3 = u[5], b3 = u[7];
            perm32swap(a2, b2); perm32swap(a3, b3);
            s16x8 pf1 = mk8(a2, a3, b2, b3);

            __builtin_amdgcn_s_setprio(1);
            accO[0] = __builtin_amdgcn_mfma_f32_32x32x16_bf16(pf0, v00, accO[0], 0, 0, 0);
            accO[1] = __builtin_amdgcn_mfma_f32_32x32x16_bf16(pf0, v01, accO[1], 0, 0, 0);
            accO[0] = __builtin_amdgcn_mfma_f32_32x32x16_bf16(pf1, v10, accO[0], 0, 0, 0);
            accO[1] = __builtin_amdgcn_mfma_f32_32x32x16_bf16(pf1, v11, accO[1], 0, 0, 0);
            __builtin_amdgcn_s_setprio(0);

            // lsum tree after PV issue — VALU fills the MFMA shadow
            lsum += (((p[0] + p[1]) + (p[2] + p[3])) + ((p[4] + p[5]) + (p[6] + p[7])))
                  + (((p[8] + p[9]) + (p[10] + p[11])) + ((p[12] + p[13]) + (p[14] + p[15])));
        }
    }

    // ---- epilogue: cross-stream merge (add partials), normalize, store bf16
    lsum += __shfl_xor(lsum, 32);
    if (hi == 0) Lred[wave][l31] = lsum;       // partial sum (NOT inverted)
    __syncthreads();                            // all chunk compute done; LDS reusable

    // merge buffer: 8 KB per wq pair, carved from stream-0's Ks/Vs
    float* mb = (wq < 2) ? (float*)&Ks[0][wq][0] : (float*)&Vs[0][wq - 2][0];
    if (ws == 1) {
#pragma unroll
        for (int jd = 0; jd < 2; ++jd)
#pragma unroll
            for (int rg = 0; rg < 4; ++rg) {
                f32x4 vv = { accO[jd][rg * 4 + 0], accO[jd][rg * 4 + 1],
                             accO[jd][rg * 4 + 2], accO[jd][rg * 4 + 3] };
                *(f32x4*)&mb[((jd * 4 + rg) << 8) + (lane << 2)] = vv;
            }
    }
    __syncthreads();
    if (ws == 0) {
#pragma unroll
        for (int jd = 0; jd < 2; ++jd)
#pragma unroll
            for (int rg = 0; rg < 4; ++rg) {
                f32x4 vv = *(const f32x4*)&mb[((jd * 4 + rg) << 8) + (lane << 2)];
                accO[jd][rg * 4 + 0] += vv[0];
                accO[jd][rg * 4 + 1] += vv[1];
                accO[jd][rg * 4 + 2] += vv[2];
                accO[jd][rg * 4 + 3] += vv[3];
            }
#pragma unroll
        for (int jd = 0; jd < 2; ++jd)
#pragma unroll
            for (int r = 0; r < 16; ++r) {
                int qrow = (r & 3) + 8 * (r >> 2) + 4 * hi;
                float inv = 1.f / (Lred[wq][qrow] + Lred[wq + 4][qrow]);
                float val = accO[jd][r] * inv;
                Hout[(size_t)(b * 2048 + q0 + wq * 32 + qrow) * 1024 + h * 64 + jd * 32 + l31] =
                    (unsigned short)pkbf16(val, val);
            }
    }
}

// ---------------------------------------------------------------------------
// gate_g: g[tok] = 2*sw0 + 6*sw1*top3sum from logits = h*Wg^T + bias.
// Side job: converts Wp fp32->bf16 into wpb (region free after attn).
// ---------------------------------------------------------------------------
__global__ __launch_bounds__(256) void gate_g(
    const unsigned short* __restrict__ Hb,   // raw h [4096][1024]
    const unsigned short* __restrict__ Wg,   // rows 0..16 bf16
    const float* __restrict__ br, const float* __restrict__ bs,
    const float* __restrict__ Wp, unsigned short* __restrict__ wpb,
    float* __restrict__ g)
{
    __shared__ __attribute__((aligned(16))) unsigned short As[4][16 * 64];
    __shared__ __attribute__((aligned(16))) unsigned short Gs[4][32 * 64];
    __shared__ float Lred[4][16][32];
    const int t = threadIdx.x, wave = t >> 6, lane = t & 63;
    const int lr = lane & 15, lq = lane >> 4;
    const int m0 = blockIdx.x * 16;
    const int srow = lane >> 3;
    const int scol = (((lane & 7) ^ srow) << 3);

    // Wp convert side-job: 512 cvt8 units per block (131072 total / 256 blocks)
    cvt8(Wp, wpb, blockIdx.x * 512 + t);
    cvt8(Wp, wpb, blockIdx.x * 512 + 256 + t);

    f32x4 acc[2];
    acc[0] = (f32x4){0.f, 0.f, 0.f, 0.f};
    acc[1] = (f32x4){0.f, 0.f, 0.f, 0.f};

    for (int k0 = wave * 64; k0 < 1024; k0 += 256) {
        gl_lds16(&Hb[(size_t)(m0 + srow) * 1024 + k0 + scol], &As[wave][0]);
        gl_lds16(&Hb[(size_t)(m0 + 8 + srow) * 1024 + k0 + scol], &As[wave][8 * 64]);
#pragma unroll
        for (int i = 0; i < 4; ++i) {
            int row = i * 8 + srow;
            int wr = (row > 16) ? 16 : row;   // clamp: no OOB
            gl_lds16(&Wg[(size_t)wr * 1024 + k0 + scol], &Gs[wave][i * 8 * 64]);
        }
        __syncthreads();   // uniform trip count across waves
#pragma unroll
        for (int kk = 0; kk < 64; kk += 32) {
            const int po = ((((kk >> 3) + lq) ^ (lr & 7)) << 3);
            s16x8 af = *(const s16x8*)&As[wave][lr * 64 + po];
#pragma unroll
            for (int j = 0; j < 2; ++j) {
                s16x8 gf = *(const s16x8*)&Gs[wave][(j * 16 + lr) * 64 + po];
                acc[j] = __builtin_amdgcn_mfma_f32_16x16x32_bf16(af, gf, acc[j], 0, 0, 0);
            }
        }
    }
#pragma unroll
    for (int j = 0; j < 2; ++j)
#pragma unroll
        for (int r = 0; r < 4; ++r)
            Lred[wave][lq * 4 + r][j * 16 + lr] = acc[j][r];
    __syncthreads();
    if (t < 16) {
        float lg[17];
#pragma unroll
        for (int j = 0; j < 17; ++j)
            lg[j] = Lred[0][t][j] + Lred[1][t][j] + Lred[2][t][j] + Lred[3][t][j]
                  + ((j < 15) ? br[j] : bs[j - 15]);
        float mx = lg[0];
#pragma unroll
        for (int j = 1; j < 15; ++j) mx = fmaxf(mx, lg[j]);
        float sum = 0.f, v1 = -1.f, v2 = -1.f, v3 = -1.f;
#pragma unroll
        for (int j = 0; j < 15; ++j) {
            float e = __expf(lg[j] - mx);
            sum += e;
            if (e > v1)      { v3 = v2; v2 = v1; v1 = e; }
            else if (e > v2) { v3 = v2; v2 = e; }
            else if (e > v3) { v3 = e; }
        }
        float tops = (v1 + v2 + v3) / sum;
        float sm = fmaxf(lg[15], lg[16]);
        float e0 = __expf(lg[15] - sm), e1 = __expf(lg[16] - sm);
        float inv = 1.f / (e0 + e1);
        g[m0 + t] = 2.f * (e0 * inv) + 6.f * (e1 * inv) * tops;
    }
}

// ---------------------------------------------------------------------------
// Out-proj GEMM: out[m][:] = g[m] * (h·Wp^T)[m][:] + bp   (row-scale commutes)
// 64x64 tile, grid 1024 = 4 blocks/CU; 2x2 waves of 32x32.
// ---------------------------------------------------------------------------
__global__ __launch_bounds__(256) void gemm64_out(
    const unsigned short* __restrict__ A,
    const unsigned short* __restrict__ Bw,
    const float* __restrict__ bias,
    const float* __restrict__ g,
    float* __restrict__ C)
{
    __shared__ __attribute__((aligned(16))) unsigned short As[64 * 64];
    __shared__ __attribute__((aligned(16))) unsigned short Bs[64 * 64];
    const int t = threadIdx.x, wave = t >> 6, lane = t & 63;
    const int lr = lane & 15, lq = lane >> 4;
    const int m0 = blockIdx.x * 64, n0 = blockIdx.y * 64;
    const int wm = (wave >> 1) * 32, wn = (wave & 1) * 32;
    const int srow = lane >> 3;
    const int scol = (((lane & 7) ^ srow) << 3);

    f32x4 acc[2][2];
#pragma unroll
    for (int i = 0; i < 2; ++i)
#pragma unroll
        for (int j = 0; j < 2; ++j) acc[i][j] = (f32x4){0.f, 0.f, 0.f, 0.f};

    for (int k0 = 0; k0 < 1024; k0 += 64) {
        __syncthreads();
#pragma unroll
        for (int i = 0; i < 2; ++i) {
            int rb = wave * 16 + i * 8;
            gl_lds16(&A[(size_t)(m0 + rb + srow) * 1024 + k0 + scol], &As[rb * 64]);
            gl_lds16(&Bw[(size_t)(n0 + rb + srow) * 1024 + k0 + scol], &Bs[rb * 64]);
        }
        __syncthreads();
#pragma unroll
        for (int kk = 0; kk < 64; kk += 32) {
            const int po = ((((kk >> 3) + lq) ^ (lr & 7)) << 3);
            s16x8 af[2], bf[2];
#pragma unroll
            for (int i = 0; i < 2; ++i)
                af[i] = *(const s16x8*)&As[(wm + i * 16 + lr) * 64 + po];
#pragma unroll
            for (int j = 0; j < 2; ++j)
                bf[j] = *(const s16x8*)&Bs[(wn + j * 16 + lr) * 64 + po];
#pragma unroll
            for (int i = 0; i < 2; ++i)
#pragma unroll
                for (int j = 0; j < 2; ++j)
                    acc[i][j] = __builtin_amdgcn_mfma_f32_16x16x32_bf16(af[i], bf[j], acc[i][j], 0, 0, 0);
        }
    }
#pragma unroll
    for (int i = 0; i < 2; ++i) {
        const float4 gi = *(const float4*)&g[m0 + wm + i * 16 + lq * 4];
        float gv[4] = {gi.x, gi.y, gi.z, gi.w};
#pragma unroll
        for (int j = 0; j < 2; ++j) {
            int col = n0 + wn + j * 16 + lr;
            float bv = bias[col];
            int rowb = m0 + wm + i * 16 + lq * 4;
#pragma unroll
            for (int r = 0; r < 4; ++r)
                C[(size_t)(rowb + r) * 1024 + col] = acc[i][j][r] * gv[r] + bv;
        }
    }
}

// ---------------------------------------------------------------------------
extern "C" void kernel_launch(void* const* d_in, const int* in_sizes, int n_in,
                              void* d_out, int out_size, void* d_ws, size_t ws_size,
                              hipStream_t stream)
{
    (void)in_sizes; (void)n_in; (void)out_size; (void)ws_size;
    const float* x   = (const float*)d_in[0];
    const float* Wq  = (const float*)d_in[1];
    const float* bq  = (const float*)d_in[2];
    const float* Wk  = (const float*)d_in[3];
    const float* bk  = (const float*)d_in[4];
    const float* Wv  = (const float*)d_in[5];
    const float* bv  = (const float*)d_in[6];
    const float* Wp  = (const float*)d_in[7];
    const float* bp  = (const float*)d_in[8];
    const float* Wr  = (const float*)d_in[9];
    const float* br  = (const float*)d_in[10];
    const float* Ws  = (const float*)d_in[11];
    const float* bs  = (const float*)d_in[12];
    const float* temperature = (const float*)d_in[13];
    const float* qe  = (const float*)d_in[14];
    float* out = (float*)d_out;

    const size_t MB = 1048576;
    unsigned short* qb   = (unsigned short*)d_ws;                     // 8 MiB (q; wpb after attn)
    unsigned short* kb   = (unsigned short*)((char*)d_ws + 8 * MB);   // 8 MiB
    unsigned short* hb   = (unsigned short*)((char*)d_ws + 16 * MB);  // 8 MiB (raw h)
    unsigned short* wqkv = (unsigned short*)((char*)d_ws + 24 * MB);  // 6 MiB
    unsigned short* wg   = (unsigned short*)((char*)d_ws + 30 * MB);  // 34 KiB
    float*          bqkv = (float*)((char*)d_ws + 30 * MB + 65536);   // 12 KiB
    float*          gbuf = (float*)((char*)d_ws + 30 * MB + 131072);  // 16 KiB
    // d_out doubles as scratch until the final GEMM:
    unsigned short* xb = (unsigned short*)d_out;                      // 8 MiB
    unsigned short* vt = xb + 4 * MB;                                 // 8 MiB V^T
    unsigned short* wpb = qb;                                         // Wp bf16 (qb dead after attn)

    dim3 blk(256);
    cvt_main<<<dim3(3605), blk, 0, stream>>>(x, Wq, Wk, Wv, Wr, Ws, bq, bk, bv,
                                             xb, wqkv, wg, bqkv);
    qkv_gemm<<<dim3(32, 24), blk, 0, stream>>>(xb, wqkv, bqkv, qb, kb, vt);
    attn_kernel<<<dim3(32, 16), dim3(512), 0, stream>>>(qb, kb, vt, temperature, qe, hb);
    gate_g<<<dim3(256), blk, 0, stream>>>(hb, wg, br, bs, Wp, wpb, gbuf);
    gemm64_out<<<dim3(64, 16), blk, 0, stream>>>(hb, wpb, bp, gbuf, out);
}

// Round 4
// 211.170 us; speedup vs baseline: 1.0406x; 1.0406x over previous
//
#include <hip/hip_runtime.h>
#include <hip/hip_bf16.h>

typedef short s16x8 __attribute__((ext_vector_type(8)));
typedef float f32x4 __attribute__((ext_vector_type(4)));
typedef float f32x16 __attribute__((ext_vector_type(16)));

__device__ __forceinline__ float b2f(unsigned short u) {
    union { unsigned int i; float f; } v;
    v.i = ((unsigned int)u) << 16;
    return v.f;
}
// packed fp32x2 -> bf16x2 (v_cvt_pk_bf16_f32 on gfx950); lo = a, hi = b
__device__ __forceinline__ unsigned int pkbf16(float a, float b) {
    union { __hip_bfloat162 h; unsigned int u; } v;
    v.h = __float22bfloat162_rn(make_float2(a, b));
    return v.u;
}
// raw v_exp_f32 — libm exp2f adds clamp/scale VALU (measured regression r5)
__device__ __forceinline__ float fast_exp2(float x) {
#if __has_builtin(__builtin_amdgcn_exp2f)
    return __builtin_amdgcn_exp2f(x);
#else
    return exp2f(x);
#endif
}

// async global->LDS, 16B/lane; LDS dest = wave-uniform base + lane*16
__device__ __forceinline__ void gl_lds16(const unsigned short* g, unsigned short* l) {
    __builtin_amdgcn_global_load_lds(
        (const __attribute__((address_space(1))) void*)g,
        (__attribute__((address_space(3))) void*)l, 16, 0, 0);
}

// v_permlane32_swap_b32: new_a = [a_lo | b_lo], new_b = [a_hi | b_hi]
__device__ __forceinline__ void perm32swap(unsigned int &a, unsigned int &b) {
    asm("v_permlane32_swap_b32 %0, %1" : "+v"(a), "+v"(b));
}

// assemble s16x8 fragment from 4 packed bf16x2 words
__device__ __forceinline__ s16x8 mk8(unsigned int a, unsigned int b,
                                     unsigned int c, unsigned int d) {
    union { uint4 u; s16x8 h; } v;
    v.u = make_uint4(a, b, c, d);
    return v.h;
}

// ---------------------------------------------------------------------------
// Merged fp32->bf16 converts + bias pack, one launch.
// ---------------------------------------------------------------------------
__device__ __forceinline__ void cvt8(const float* __restrict__ s,
                                     unsigned short* __restrict__ d, int i) {
    const float* p = s + (size_t)i * 8;
    float4 a = *(const float4*)p;
    float4 b = *(const float4*)(p + 4);
    unsigned int u0 = pkbf16(a.x, a.y), u1 = pkbf16(a.z, a.w);
    unsigned int u2 = pkbf16(b.x, b.y), u3 = pkbf16(b.z, b.w);
    uint4 o = {u0, u1, u2, u3};
    *(uint4*)&d[(size_t)i * 8] = o;
}

__global__ __launch_bounds__(256) void cvt_main(
    const float* __restrict__ x,  const float* __restrict__ Wq,
    const float* __restrict__ Wk, const float* __restrict__ Wv,
    const float* __restrict__ Wr, const float* __restrict__ Ws,
    const float* __restrict__ bq, const float* __restrict__ bk,
    const float* __restrict__ bv,
    unsigned short* __restrict__ xb, unsigned short* __restrict__ wqkv,
    unsigned short* __restrict__ wg, float* __restrict__ bqkv)
{
    int blk = blockIdx.x, t = threadIdx.x;
    if (blk < 2048)      cvt8(x,  xb,             blk * 256 + t);
    else if (blk < 2560) cvt8(Wq, wqkv,           (blk - 2048) * 256 + t);
    else if (blk < 3072) cvt8(Wk, wqkv + 1048576, (blk - 2560) * 256 + t);
    else if (blk < 3584) cvt8(Wv, wqkv + 2097152, (blk - 3072) * 256 + t);
    else if (blk < 3592) { int i = (blk - 3584) * 256 + t; if (i < 1920) cvt8(Wr, wg, i); }
    else if (blk < 3593) { int i = t; cvt8(Ws, wg + 15360, i); }
    else {
        int i = (blk - 3593) * 256 + t;  // 0..3071
        bqkv[i] = (i < 1024) ? bq[i] : (i < 2048) ? bk[i - 1024] : bv[i - 2048];
    }
}

// ---------------------------------------------------------------------------
// QKV GEMM: C = xb[4096][1024] * Wqkv[3072][1024]^T + bias.
// 128x128 tile, BK=64, swizzled LDS + global_load_lds.
// n0<1024 -> Q; <2048 -> K; else V written transposed to Vt[b,h,d,tok].
// NOTE: NOT double-buffered on purpose — 64KB LDS would cut occupancy 3->2
// blocks/CU (m132-class regression). Implicit wave overlap covers staging.
// ---------------------------------------------------------------------------
__global__ __launch_bounds__(256) void qkv_gemm(
    const unsigned short* __restrict__ A,
    const unsigned short* __restrict__ Bw,
    const float* __restrict__ bias,
    unsigned short* __restrict__ Q, unsigned short* __restrict__ K,
    unsigned short* __restrict__ Vt)
{
    __shared__ __attribute__((aligned(16))) unsigned short As[128 * 64];
    __shared__ __attribute__((aligned(16))) unsigned short Bs[128 * 64];
    const int t = threadIdx.x;
    const int wave = t >> 6, lane = t & 63;
    const int m0 = blockIdx.x * 128, n0 = blockIdx.y * 128;
    const int wm = (wave >> 1) * 64, wn = (wave & 1) * 64;
    const int lr = lane & 15, lq = lane >> 4;
    const int srow = lane >> 3;
    const int scol = (((lane & 7) ^ srow) << 3);

    f32x4 acc[4][4];
#pragma unroll
    for (int i = 0; i < 4; ++i)
#pragma unroll
        for (int j = 0; j < 4; ++j) acc[i][j] = (f32x4){0.f, 0.f, 0.f, 0.f};

    for (int k0 = 0; k0 < 1024; k0 += 64) {
        __syncthreads();
#pragma unroll
        for (int i = 0; i < 4; ++i) {
            int rb = wave * 32 + i * 8;
            gl_lds16(&A[(size_t)(m0 + rb + srow) * 1024 + k0 + scol], &As[rb * 64]);
            gl_lds16(&Bw[(size_t)(n0 + rb + srow) * 1024 + k0 + scol], &Bs[rb * 64]);
        }
        __syncthreads();
#pragma unroll
        for (int kk = 0; kk < 64; kk += 32) {
            const int po = ((((kk >> 3) + lq) ^ (lr & 7)) << 3);
            s16x8 af[4], bf[4];
#pragma unroll
            for (int i = 0; i < 4; ++i)
                af[i] = *(const s16x8*)&As[(wm + i * 16 + lr) * 64 + po];
#pragma unroll
            for (int j = 0; j < 4; ++j)
                bf[j] = *(const s16x8*)&Bs[(wn + j * 16 + lr) * 64 + po];
#pragma unroll
            for (int i = 0; i < 4; ++i)
#pragma unroll
                for (int j = 0; j < 4; ++j)
                    acc[i][j] = __builtin_amdgcn_mfma_f32_16x16x32_bf16(af[i], bf[j], acc[i][j], 0, 0, 0);
        }
    }
    const int kind = n0 >> 10;        // 0=Q 1=K 2=V
    const int nc = n0 & 1023;
    if (kind < 2) {
        unsigned short* Cm = kind ? K : Q;
#pragma unroll
        for (int j = 0; j < 4; ++j) {
            int cl = wn + j * 16 + lr;
            float bv = bias[n0 + cl];
#pragma unroll
            for (int i = 0; i < 4; ++i) {
                int rowb = m0 + wm + i * 16 + lq * 4;
                unsigned int u0 = pkbf16(acc[i][j][0] + bv, acc[i][j][1] + bv);
                unsigned int u1 = pkbf16(acc[i][j][2] + bv, acc[i][j][3] + bv);
                Cm[(size_t)(rowb + 0) * 1024 + nc + cl] = (unsigned short)u0;
                Cm[(size_t)(rowb + 1) * 1024 + nc + cl] = (unsigned short)(u0 >> 16);
                Cm[(size_t)(rowb + 2) * 1024 + nc + cl] = (unsigned short)u1;
                Cm[(size_t)(rowb + 3) * 1024 + nc + cl] = (unsigned short)(u1 >> 16);
            }
        }
    } else {
        // V -> Vt[b,h,d,tok]: 4 consecutive tokens per lane = 8B contiguous
        const int bb = m0 >> 11;
#pragma unroll
        for (int j = 0; j < 4; ++j) {
            int col = nc + wn + j * 16 + lr;      // channel 0..1023
            int hh = col >> 6, dd = col & 63;
            float bv = bias[n0 + wn + j * 16 + lr];
#pragma unroll
            for (int i = 0; i < 4; ++i) {
                int tokb = m0 + wm + i * 16 + lq * 4;
                int tloc = tokb & 2047;
                uint2 u;
                u.x = pkbf16(acc[i][j][0] + bv, acc[i][j][1] + bv);
                u.y = pkbf16(acc[i][j][2] + bv, acc[i][j][3] + bv);
                *(uint2*)&Vt[((size_t)(bb * 16 + hh) * 64 + dd) * 2048 + tloc] = u;
            }
        }
    }
}

// ---------------------------------------------------------------------------
// Flash attention v3 (r13 REVERT, proven 56.7us): in-block K-split, swapped
// 32x32x16 MFMA, in-reg softmax (cvt_pk + permlane32_swap), double-buffered
// 64-key chunks, wave skew. r14's two-half pipeline REVERTED: keeping both
// halves' S matrices live spilled to scratch (WRITE_SIZE 8->19.5 MB) — T15
// violated its VGPR-budget prereq at this accumulator footprint.
// ---------------------------------------------------------------------------
__global__ __launch_bounds__(512, 4) void attn_kernel(
    const unsigned short* __restrict__ Q,   // raw q [B*N][C]
    const unsigned short* __restrict__ Kb,  // [B*N][C]
    const unsigned short* __restrict__ Vt,  // [B][H][64][N]
    const float* __restrict__ temp,
    const float* __restrict__ qe,
    unsigned short* __restrict__ Hout)      // [B*N][C]
{
    __shared__ __attribute__((aligned(16))) unsigned short Ks[2][2][64 * 64]; // [stream][buf] 32 KB
    __shared__ __attribute__((aligned(16))) unsigned short Vs[2][2][64 * 64]; // 32 KB
    __shared__ float Lred[8][32];                                             // 1 KB
    const int t = threadIdx.x, wave = t >> 6, lane = t & 63;
    const int ws = wave >> 2, wq = wave & 3;   // key-stream, q-subtile wave
    const int l31 = lane & 31, hi = lane >> 5;
    const int bh = blockIdx.x, b = bh >> 4, h = bh & 15;
    const int q0 = blockIdx.y * 128;
    const int srow = lane >> 3;
    const int scol = (((lane & 7) ^ srow) << 3);
    const int kbase = ws << 10;                // stream key offset (0 / 1024)
    unsigned short* KsF = &Ks[0][0][0];        // flat 16 KB region for Q staging

    auto stageK = [&](int kc, int cb) {
#pragma unroll
        for (int i2 = 0; i2 < 2; ++i2) {
            int rb = wq * 16 + i2 * 8;
            gl_lds16(&Kb[(size_t)(b * 2048 + kbase + kc + rb + srow) * 1024 + h * 64 + scol],
                     &Ks[ws][cb][rb * 64]);
        }
    };
    auto stageV = [&](int kc, int cb) {
#pragma unroll
        for (int i2 = 0; i2 < 2; ++i2) {
            int rb = wq * 16 + i2 * 8;
            gl_lds16(&Vt[((size_t)(b * 16 + h) * 64 + rb + srow) * 2048 + kbase + kc + scol],
                     &Vs[ws][cb][rb * 64]);
        }
    };

    // ---- prologue: stage raw Q (swizzled), 8 waves x 16 rows = 128 rows
    {
        int rb = wave * 16;
        gl_lds16(&Q[(size_t)(b * 2048 + q0 + rb + srow) * 1024 + h * 64 + scol],
                 &KsF[rb * 64]);
        gl_lds16(&Q[(size_t)(b * 2048 + q0 + rb + 8 + srow) * 1024 + h * 64 + scol],
                 &KsF[(rb + 8) * 64]);
    }
    __syncthreads();

    // Q fragments: lane (l31,hi) reads q-row wq*32+l31, d = kd*16+hi*8..+7
    s16x8 qf[4];
#pragma unroll
    for (int kd = 0; kd < 4; ++kd)
        qf[kd] = *(const s16x8*)&KsF[(wq * 32 + l31) * 64 + (((kd * 2 + hi) ^ (l31 & 7)) << 3)];
    __syncthreads();   // all Q reads complete before chunk-0 staging reuses Ks

    // issue chunk-0 stage now; the q' VALU math below overlaps its flight
    stageK(0, 0);
    stageV(0, 0);

    // q' = (q/||q|| + qe[h]) * softplus(temp[h]) / (8 ln2), into B-fragments.
    float tv = temp[h];
    float sp = ((tv > 20.f) ? tv : log1pf(__expf(tv))) * 0.18033688f;
    s16x8 aqB[4];
    {
        float v[4][8];
        float ss = 0.f;
#pragma unroll
        for (int kd = 0; kd < 4; ++kd)
#pragma unroll
            for (int e = 0; e < 8; ++e) {
                v[kd][e] = b2f((unsigned short)qf[kd][e]);
                ss += v[kd][e] * v[kd][e];
            }
        ss += __shfl_xor(ss, 32);   // partner lane holds the other 32 d's
        float rn = rsqrtf(ss);
#pragma unroll
        for (int kd = 0; kd < 4; ++kd) {
            const float* qh = qe + h * 64 + kd * 16 + hi * 8;
            unsigned int w0 = pkbf16((v[kd][0] * rn + qh[0]) * sp, (v[kd][1] * rn + qh[1]) * sp);
            unsigned int w1 = pkbf16((v[kd][2] * rn + qh[2]) * sp, (v[kd][3] * rn + qh[3]) * sp);
            unsigned int w2 = pkbf16((v[kd][4] * rn + qh[4]) * sp, (v[kd][5] * rn + qh[5]) * sp);
            unsigned int w3 = pkbf16((v[kd][6] * rn + qh[6]) * sp, (v[kd][7] * rn + qh[7]) * sp);
            aqB[kd] = mk8(w0, w1, w2, w3);
        }
    }

    f32x16 accO[2];
#pragma unroll
    for (int r = 0; r < 16; ++r) { accO[0][r] = 0.f; accO[1][r] = 0.f; }
    float lsum = 0.f;

    for (int it = 0; it < 16; ++it) {
        const int c = it & 1;
        __syncthreads();   // chunk it staged (vmcnt drained); prev-buf reads done
        if (it < 15) { stageK((it + 1) * 64, c ^ 1); stageV((it + 1) * 64, c ^ 1); }

#pragma unroll
        for (int jj = 0; jj < 2; ++jj) {
            const int j = jj ^ (wave & 1);   // wave skew: spread pipe phases

            // S^T = K * Q^T over d=64 (4 chained K=16 MFMAs)
            s16x8 kf[4];
#pragma unroll
            for (int kd = 0; kd < 4; ++kd)
                kf[kd] = *(const s16x8*)&Ks[ws][c][(j * 32 + l31) * 64 + (((kd * 2 + hi) ^ (l31 & 7)) << 3)];
            f32x16 s;
#pragma unroll
            for (int r = 0; r < 16; ++r) s[r] = 0.f;
            __builtin_amdgcn_s_setprio(1);
#pragma unroll
            for (int kd = 0; kd < 4; ++kd)
                s = __builtin_amdgcn_mfma_f32_32x32x16_bf16(kf[kd], aqB[kd], s, 0, 0, 0);
            __builtin_amdgcn_s_setprio(0);

            // p = 2^s (m=0 softmax, proven numerics); l accumulates per q=l31
            float p[16];
#pragma unroll
            for (int r = 0; r < 16; ++r) p[r] = fast_exp2(s[r]);
            lsum += (((p[0] + p[1]) + (p[2] + p[3])) + ((p[4] + p[5]) + (p[6] + p[7])))
                  + (((p[8] + p[9]) + (p[10] + p[11])) + ((p[12] + p[13]) + (p[14] + p[15])));
            unsigned int u[8];
#pragma unroll
            for (int g = 0; g < 8; ++g) u[g] = pkbf16(p[2 * g], p[2 * g + 1]);

            // P -> A-fragments in-register; O += P * V
#pragma unroll
            for (int kh = 0; kh < 2; ++kh) {
                unsigned int a0 = u[4 * kh + 0], b0 = u[4 * kh + 2];
                unsigned int a1 = u[4 * kh + 1], b1 = u[4 * kh + 3];
                perm32swap(a0, b0);   // a0 -> frag w0, b0 -> frag w2
                perm32swap(a1, b1);   // a1 -> frag w1, b1 -> frag w3
                s16x8 pf = mk8(a0, a1, b0, b1);
                const int vb = (((j * 4 + kh * 2 + hi) ^ (l31 & 7)) << 3);
                s16x8 v0 = *(const s16x8*)&Vs[ws][c][(l31) * 64 + vb];
                s16x8 v1 = *(const s16x8*)&Vs[ws][c][(32 + l31) * 64 + vb];
                __builtin_amdgcn_s_setprio(1);
                accO[0] = __builtin_amdgcn_mfma_f32_32x32x16_bf16(pf, v0, accO[0], 0, 0, 0);
                accO[1] = __builtin_amdgcn_mfma_f32_32x32x16_bf16(pf, v1, accO[1], 0, 0, 0);
                __builtin_amdgcn_s_setprio(0);
            }
        }
    }

    // ---- epilogue: cross-stream merge (add partials), normalize, store bf16
    lsum += __shfl_xor(lsum, 32);
    if (hi == 0) Lred[wave][l31] = lsum;       // partial sum (NOT inverted)
    __syncthreads();                            // all chunk compute done; LDS reusable

    // merge buffer: 8 KB per wq pair, carved from stream-0's Ks/Vs
    float* mb = (wq < 2) ? (float*)&Ks[0][wq][0] : (float*)&Vs[0][wq - 2][0];
    if (ws == 1) {
#pragma unroll
        for (int jd = 0; jd < 2; ++jd)
#pragma unroll
            for (int rg = 0; rg < 4; ++rg) {
                f32x4 vv = { accO[jd][rg * 4 + 0], accO[jd][rg * 4 + 1],
                             accO[jd][rg * 4 + 2], accO[jd][rg * 4 + 3] };
                *(f32x4*)&mb[((jd * 4 + rg) << 8) + (lane << 2)] = vv;
            }
    }
    __syncthreads();
    if (ws == 0) {
#pragma unroll
        for (int jd = 0; jd < 2; ++jd)
#pragma unroll
            for (int rg = 0; rg < 4; ++rg) {
                f32x4 vv = *(const f32x4*)&mb[((jd * 4 + rg) << 8) + (lane << 2)];
                accO[jd][rg * 4 + 0] += vv[0];
                accO[jd][rg * 4 + 1] += vv[1];
                accO[jd][rg * 4 + 2] += vv[2];
                accO[jd][rg * 4 + 3] += vv[3];
            }
#pragma unroll
        for (int jd = 0; jd < 2; ++jd)
#pragma unroll
            for (int r = 0; r < 16; ++r) {
                int qrow = (r & 3) + 8 * (r >> 2) + 4 * hi;
                float inv = 1.f / (Lred[wq][qrow] + Lred[wq + 4][qrow]);
                float val = accO[jd][r] * inv;
                Hout[(size_t)(b * 2048 + q0 + wq * 32 + qrow) * 1024 + h * 64 + jd * 32 + l31] =
                    (unsigned short)pkbf16(val, val);
            }
    }
}

// ---------------------------------------------------------------------------
// gate_g: g[tok] = 2*sw0 + 6*sw1*top3sum from logits = h*Wg^T + bias.
// Side job: converts Wp fp32->bf16 into wpb (region free after attn).
// r15: in-loop __syncthreads removed — As[wave]/Gs[wave] are per-wave
// private, so a per-wave vmcnt(0) on own global_load_lds suffices (no
// cross-wave convoy). Final block-wide barrier before Lred retained.
// ---------------------------------------------------------------------------
__global__ __launch_bounds__(256) void gate_g(
    const unsigned short* __restrict__ Hb,   // raw h [4096][1024]
    const unsigned short* __restrict__ Wg,   // rows 0..16 bf16
    const float* __restrict__ br, const float* __restrict__ bs,
    const float* __restrict__ Wp, unsigned short* __restrict__ wpb,
    float* __restrict__ g)
{
    __shared__ __attribute__((aligned(16))) unsigned short As[4][16 * 64];
    __shared__ __attribute__((aligned(16))) unsigned short Gs[4][32 * 64];
    __shared__ float Lred[4][16][32];
    const int t = threadIdx.x, wave = t >> 6, lane = t & 63;
    const int lr = lane & 15, lq = lane >> 4;
    const int m0 = blockIdx.x * 16;
    const int srow = lane >> 3;
    const int scol = (((lane & 7) ^ srow) << 3);

    // Wp convert side-job: 512 cvt8 units per block (131072 total / 256 blocks)
    cvt8(Wp, wpb, blockIdx.x * 512 + t);
    cvt8(Wp, wpb, blockIdx.x * 512 + 256 + t);

    f32x4 acc[2];
    acc[0] = (f32x4){0.f, 0.f, 0.f, 0.f};
    acc[1] = (f32x4){0.f, 0.f, 0.f, 0.f};

    for (int k0 = wave * 64; k0 < 1024; k0 += 256) {
        gl_lds16(&Hb[(size_t)(m0 + srow) * 1024 + k0 + scol], &As[wave][0]);
        gl_lds16(&Hb[(size_t)(m0 + 8 + srow) * 1024 + k0 + scol], &As[wave][8 * 64]);
#pragma unroll
        for (int i = 0; i < 4; ++i) {
            int row = i * 8 + srow;
            int wr = (row > 16) ? 16 : row;   // clamp: no OOB
            gl_lds16(&Wg[(size_t)wr * 1024 + k0 + scol], &Gs[wave][i * 8 * 64]);
        }
        // per-wave buffers: wait own async loads only (no block barrier)
        asm volatile("s_waitcnt vmcnt(0)" ::: "memory");
#pragma unroll
        for (int kk = 0; kk < 64; kk += 32) {
            const int po = ((((kk >> 3) + lq) ^ (lr & 7)) << 3);
            s16x8 af = *(const s16x8*)&As[wave][lr * 64 + po];
#pragma unroll
            for (int j = 0; j < 2; ++j) {
                s16x8 gf = *(const s16x8*)&Gs[wave][(j * 16 + lr) * 64 + po];
                acc[j] = __builtin_amdgcn_mfma_f32_16x16x32_bf16(af, gf, acc[j], 0, 0, 0);
            }
        }
    }
#pragma unroll
    for (int j = 0; j < 2; ++j)
#pragma unroll
        for (int r = 0; r < 4; ++r)
            Lred[wave][lq * 4 + r][j * 16 + lr] = acc[j][r];
    __syncthreads();
    if (t < 16) {
        float lg[17];
#pragma unroll
        for (int j = 0; j < 17; ++j)
            lg[j] = Lred[0][t][j] + Lred[1][t][j] + Lred[2][t][j] + Lred[3][t][j]
                  + ((j < 15) ? br[j] : bs[j - 15]);
        float mx = lg[0];
#pragma unroll
        for (int j = 1; j < 15; ++j) mx = fmaxf(mx, lg[j]);
        float sum = 0.f, v1 = -1.f, v2 = -1.f, v3 = -1.f;
#pragma unroll
        for (int j = 0; j < 15; ++j) {
            float e = __expf(lg[j] - mx);
            sum += e;
            if (e > v1)      { v3 = v2; v2 = v1; v1 = e; }
            else if (e > v2) { v3 = v2; v2 = e; }
            else if (e > v3) { v3 = e; }
        }
        float tops = (v1 + v2 + v3) / sum;
        float sm = fmaxf(lg[15], lg[16]);
        float e0 = __expf(lg[15] - sm), e1 = __expf(lg[16] - sm);
        float inv = 1.f / (e0 + e1);
        g[m0 + t] = 2.f * (e0 * inv) + 6.f * (e1 * inv) * tops;
    }
}

// ---------------------------------------------------------------------------
// Out-proj GEMM: out[m][:] = g[m] * (h·Wp^T)[m][:] + bp   (row-scale commutes)
// 64x64 tile, grid 1024 = 4 blocks/CU; 2x2 waves of 32x32.
// r15: converted from serial 2-barrier K-steps to single-barrier
// double-buffered pipeline (attn-proven): prologue-stage buf0, per step
// {barrier; prefetch buf^1; compute buf}. LDS 16->32 KB (still 4 blocks/CU).
// ---------------------------------------------------------------------------
__global__ __launch_bounds__(256) void gemm64_out(
    const unsigned short* __restrict__ A,
    const unsigned short* __restrict__ Bw,
    const float* __restrict__ bias,
    const float* __restrict__ g,
    float* __restrict__ C)
{
    __shared__ __attribute__((aligned(16))) unsigned short As[2][64 * 64];
    __shared__ __attribute__((aligned(16))) unsigned short Bs[2][64 * 64];
    const int t = threadIdx.x, wave = t >> 6, lane = t & 63;
    const int lr = lane & 15, lq = lane >> 4;
    const int m0 = blockIdx.x * 64, n0 = blockIdx.y * 64;
    const int wm = (wave >> 1) * 32, wn = (wave & 1) * 32;
    const int srow = lane >> 3;
    const int scol = (((lane & 7) ^ srow) << 3);

    auto stage = [&](int k0, int cb) {
#pragma unroll
        for (int i = 0; i < 2; ++i) {
            int rb = wave * 16 + i * 8;
            gl_lds16(&A[(size_t)(m0 + rb + srow) * 1024 + k0 + scol], &As[cb][rb * 64]);
            gl_lds16(&Bw[(size_t)(n0 + rb + srow) * 1024 + k0 + scol], &Bs[cb][rb * 64]);
        }
    };

    f32x4 acc[2][2];
#pragma unroll
    for (int i = 0; i < 2; ++i)
#pragma unroll
        for (int j = 0; j < 2; ++j) acc[i][j] = (f32x4){0.f, 0.f, 0.f, 0.f};

    stage(0, 0);
    for (int it = 0; it < 16; ++it) {
        const int c = it & 1;
        __syncthreads();   // buffer c staged (vmcnt drained); prev reads done
        if (it < 15) stage((it + 1) * 64, c ^ 1);
#pragma unroll
        for (int kk = 0; kk < 64; kk += 32) {
            const int po = ((((kk >> 3) + lq) ^ (lr & 7)) << 3);
            s16x8 af[2], bf[2];
#pragma unroll
            for (int i = 0; i < 2; ++i)
                af[i] = *(const s16x8*)&As[c][(wm + i * 16 + lr) * 64 + po];
#pragma unroll
            for (int j = 0; j < 2; ++j)
                bf[j] = *(const s16x8*)&Bs[c][(wn + j * 16 + lr) * 64 + po];
#pragma unroll
            for (int i = 0; i < 2; ++i)
#pragma unroll
                for (int j = 0; j < 2; ++j)
                    acc[i][j] = __builtin_amdgcn_mfma_f32_16x16x32_bf16(af[i], bf[j], acc[i][j], 0, 0, 0);
        }
    }
#pragma unroll
    for (int i = 0; i < 2; ++i) {
        const float4 gi = *(const float4*)&g[m0 + wm + i * 16 + lq * 4];
        float gv[4] = {gi.x, gi.y, gi.z, gi.w};
#pragma unroll
        for (int j = 0; j < 2; ++j) {
            int col = n0 + wn + j * 16 + lr;
            float bv = bias[col];
            int rowb = m0 + wm + i * 16 + lq * 4;
#pragma unroll
            for (int r = 0; r < 4; ++r)
                C[(size_t)(rowb + r) * 1024 + col] = acc[i][j][r] * gv[r] + bv;
        }
    }
}

// ---------------------------------------------------------------------------
extern "C" void kernel_launch(void* const* d_in, const int* in_sizes, int n_in,
                              void* d_out, int out_size, void* d_ws, size_t ws_size,
                              hipStream_t stream)
{
    (void)in_sizes; (void)n_in; (void)out_size; (void)ws_size;
    const float* x   = (const float*)d_in[0];
    const float* Wq  = (const float*)d_in[1];
    const float* bq  = (const float*)d_in[2];
    const float* Wk  = (const float*)d_in[3];
    const float* bk  = (const float*)d_in[4];
    const float* Wv  = (const float*)d_in[5];
    const float* bv  = (const float*)d_in[6];
    const float* Wp  = (const float*)d_in[7];
    const float* bp  = (const float*)d_in[8];
    const float* Wr  = (const float*)d_in[9];
    const float* br  = (const float*)d_in[10];
    const float* Ws  = (const float*)d_in[11];
    const float* bs  = (const float*)d_in[12];
    const float* temperature = (const float*)d_in[13];
    const float* qe  = (const float*)d_in[14];
    float* out = (float*)d_out;

    const size_t MB = 1048576;
    unsigned short* qb   = (unsigned short*)d_ws;                     // 8 MiB (q; wpb after attn)
    unsigned short* kb   = (unsigned short*)((char*)d_ws + 8 * MB);   // 8 MiB
    unsigned short* hb   = (unsigned short*)((char*)d_ws + 16 * MB);  // 8 MiB (raw h)
    unsigned short* wqkv = (unsigned short*)((char*)d_ws + 24 * MB);  // 6 MiB
    unsigned short* wg   = (unsigned short*)((char*)d_ws + 30 * MB);  // 34 KiB
    float*          bqkv = (float*)((char*)d_ws + 30 * MB + 65536);   // 12 KiB
    float*          gbuf = (float*)((char*)d_ws + 30 * MB + 131072);  // 16 KiB
    // d_out doubles as scratch until the final GEMM:
    unsigned short* xb = (unsigned short*)d_out;                      // 8 MiB
    unsigned short* vt = xb + 4 * MB;                                 // 8 MiB V^T
    unsigned short* wpb = qb;                                         // Wp bf16 (qb dead after attn)

    dim3 blk(256);
    cvt_main<<<dim3(3605), blk, 0, stream>>>(x, Wq, Wk, Wv, Wr, Ws, bq, bk, bv,
                                             xb, wqkv, wg, bqkv);
    qkv_gemm<<<dim3(32, 24), blk, 0, stream>>>(xb, wqkv, bqkv, qb, kb, vt);
    attn_kernel<<<dim3(32, 16), dim3(512), 0, stream>>>(qb, kb, vt, temperature, qe, hb);
    gate_g<<<dim3(256), blk, 0, stream>>>(hb, wg, br, bs, Wp, wpb, gbuf);
    gemm64_out<<<dim3(64, 16), blk, 0, stream>>>(hb, wpb, bp, gbuf, out);
}